// Round 3
// baseline (264.633 us; speedup 1.0000x reference)
//
#include <hip/hip_runtime.h>
#include <hip/hip_bf16.h>
#include <math.h>

// Problem constants (match reference)
#define BB 8
#define NN 2048
#define C_IN 64
#define NCH 64
#define NTERMS 3
#define LN_EPS 1e-5f

// ---------------------------------------------------------------------------
// Kernel 1: Xs[b,n] = sum_c X[b,n,c].  C_IN == 64 == wave size: one lane per
// channel, butterfly shuffle reduce.  4 waves / block -> 4 rows / block.
// ---------------------------------------------------------------------------
__global__ void xsum_kernel(const float* __restrict__ X, float* __restrict__ Xs) {
    int row  = (blockIdx.x * blockDim.x + threadIdx.x) >> 6;   // b*NN + n
    int lane = threadIdx.x & 63;
    float v = X[(size_t)row * C_IN + lane];
    #pragma unroll
    for (int off = 32; off > 0; off >>= 1)
        v += __shfl_down(v, off, 64);
    if (lane == 0) Xs[row] = v;
}

// ---------------------------------------------------------------------------
// Kernel 2: batched matvec  pout[b,m] = sum_n A[b,m,n] * pin[b,n]
//
// v3: register-resident p, no LDS, no barrier.
//   - each wave loads pin[b,:] (8 KB) into 8 float4 registers (32 VGPRs)
//   - 2 rows per wave, 8 rows per block -> grid (NN/8, BB) = 2048 blocks
//     (8 blocks/CU -> high occupancy; launch_bounds caps VGPR at 128 so
//      4 waves/SIMD are resident)
//   - 16 independent global float4 loads per wave, independent of the p
//     loads -> deep MLP, compiler can issue all before first waitcnt
// ---------------------------------------------------------------------------
#define MV_RPW  2                    // rows per wave
#define MV_ROWS (4 * MV_RPW)         // rows per block = 8
__global__ __launch_bounds__(256, 4) void matvec_kernel(
        const float* __restrict__ A,
        const float* __restrict__ pin,
        float* __restrict__ pout) {
    const int b    = blockIdx.y;
    const int wave = threadIdx.x >> 6;
    const int lane = threadIdx.x & 63;
    const int m    = blockIdx.x * MV_ROWS + wave * MV_RPW;

    // p[b,:] into registers: pr[j] covers elements 4*(j*64+lane) .. +3
    const float4* pin4 = (const float4*)(pin + (size_t)b * NN);
    float4 pr[8];
    #pragma unroll
    for (int j = 0; j < 8; ++j)
        pr[j] = pin4[j * 64 + lane];

    const float4* r0 = (const float4*)(A + (size_t)b * NN * NN + (size_t)m * NN);
    const float4* r1 = r0 + NN / 4;

    float a0 = 0.f, a1 = 0.f;
    #pragma unroll
    for (int it = 0; it < 8; ++it) {
        const int o = it * 64 + lane;
        float4 x0 = r0[o];
        float4 x1 = r1[o];
        a0 += x0.x * pr[it].x + x0.y * pr[it].y + x0.z * pr[it].z + x0.w * pr[it].w;
        a1 += x1.x * pr[it].x + x1.y * pr[it].y + x1.z * pr[it].z + x1.w * pr[it].w;
    }

    #pragma unroll
    for (int off = 32; off > 0; off >>= 1) {
        a0 += __shfl_down(a0, off, 64);
        a1 += __shfl_down(a1, off, 64);
    }
    if (lane == 0) {
        float2 o2 = make_float2(a0, a1);
        *(float2*)(pout + (size_t)b * NN + m) = o2;
    }
}

// ---------------------------------------------------------------------------
// Kernel 3: one WAVE per (b,n); lane = channel.
//   y = sum_i h[i,lane,n] * P[i,b,n];  LayerNorm across the wave; tanh; store.
// ---------------------------------------------------------------------------
__global__ __launch_bounds__(256) void combine_kernel(
        const float* __restrict__ h,      // [4, 64, NN]
        const float* __restrict__ P,      // [4, BB, NN]
        const float* __restrict__ gamma,  // [64]
        const float* __restrict__ beta,   // [64]
        float* __restrict__ out) {        // [BB, NN, 64]
    const int idx  = (blockIdx.x * blockDim.x + threadIdx.x) >> 6;  // b*NN + n
    const int lane = threadIdx.x & 63;                              // channel
    const int n    = idx & (NN - 1);

    const float p0 = P[0 * BB * NN + idx];
    const float p1 = P[1 * BB * NN + idx];
    const float p2 = P[2 * BB * NN + idx];
    const float p3 = P[3 * BB * NN + idx];

    float y = h[(size_t)(0 * NCH + lane) * NN + n] * p0
            + h[(size_t)(1 * NCH + lane) * NN + n] * p1
            + h[(size_t)(2 * NCH + lane) * NN + n] * p2
            + h[(size_t)(3 * NCH + lane) * NN + n] * p3;

    // mean (all-lanes butterfly)
    float s = y;
    #pragma unroll
    for (int off = 32; off > 0; off >>= 1)
        s += __shfl_xor(s, off, 64);
    const float mean = s * (1.f / NCH);

    float d = y - mean;
    float vs = d * d;
    #pragma unroll
    for (int off = 32; off > 0; off >>= 1)
        vs += __shfl_xor(vs, off, 64);
    const float rstd = rsqrtf(vs * (1.f / NCH) + LN_EPS);

    out[(size_t)idx * NCH + lane] = tanhf(d * rstd * gamma[lane] + beta[lane]);
}

// ---------------------------------------------------------------------------
extern "C" void kernel_launch(void* const* d_in, const int* in_sizes, int n_in,
                              void* d_out, int out_size, void* d_ws, size_t ws_size,
                              hipStream_t stream) {
    const float* A     = (const float*)d_in[0];  // [B, N, N]
    const float* X     = (const float*)d_in[1];  // [B, N, C_IN]
    const float* h     = (const float*)d_in[2];  // [4, 64, N]
    const float* gamma = (const float*)d_in[3];  // [64]
    const float* beta  = (const float*)d_in[4];  // [64]
    float* out = (float*)d_out;                  // [B, N, 64]

    // workspace: P[4][B][N] floats = 256 KB
    float* P = (float*)d_ws;

    // 1) P[0] = Xs = rowsum(X)
    {
        int rows = BB * NN;                 // 16384 rows, 4 rows/block
        xsum_kernel<<<rows / 4, 256, 0, stream>>>(X, P);
    }

    // 2) P[i] = A @ P[i-1], i = 1..3  (sequential dependency)
    dim3 mv_grid(NN / MV_ROWS, BB);
    for (int i = 1; i <= NTERMS; ++i) {
        matvec_kernel<<<mv_grid, 256, 0, stream>>>(
            A, P + (size_t)(i - 1) * BB * NN, P + (size_t)i * BB * NN);
    }

    // 3) combine + LayerNorm + tanh  (wave per (b,n): 16384 waves)
    combine_kernel<<<(BB * NN * 64) / 256, 256, 0, stream>>>(h, P, gamma, beta, out);
}

// Round 4
// 254.181 us; speedup vs baseline: 1.0411x; 1.0411x over previous
//
#include <hip/hip_runtime.h>
#include <hip/hip_bf16.h>
#include <math.h>

// Problem constants (match reference)
#define BB 8
#define NN 2048
#define C_IN 64
#define NCH 64
#define NTERMS 3
#define LN_EPS 1e-5f

// ---------------------------------------------------------------------------
// Kernel 1: Xs[b,n] = sum_c X[b,n,c].  C_IN == 64 == wave size: one lane per
// channel, butterfly shuffle reduce.  4 waves / block -> 4 rows / block.
// ---------------------------------------------------------------------------
__global__ void xsum_kernel(const float* __restrict__ X, float* __restrict__ Xs) {
    int row  = (blockIdx.x * blockDim.x + threadIdx.x) >> 6;   // b*NN + n
    int lane = threadIdx.x & 63;
    float v = X[(size_t)row * C_IN + lane];
    #pragma unroll
    for (int off = 32; off > 0; off >>= 1)
        v += __shfl_down(v, off, 64);
    if (lane == 0) Xs[row] = v;
}

// ---------------------------------------------------------------------------
// Kernel 2 (v4): batched matvec  pout[b,m] = sum_n A[b,m,n] * pin[b,n]
//
// Wave-churn streaming design (mimics the 6.3 TB/s copy pattern):
//   - ONE row per wave; wave issues its 8 independent float4 A-loads in one
//     burst into registers, dots against LDS-staged p, reduces, retires.
//   - lean VGPR (~48) + __launch_bounds__(256,8) -> 8 waves/SIMD,
//     32 waves/CU, 8 blocks/CU (LDS 8 KB/block x 8 = 64 KB < 160 KB).
//   - grid (NN/4, BB) = 4096 blocks -> constant wave churn; consecutive
//     blocks read consecutive A rows (good DRAM/XCD striping).
//   - p reads via ds_read (lgkmcnt) never gate the A-load vmcnt waits.
// ---------------------------------------------------------------------------
__global__ __launch_bounds__(256, 8) void matvec_kernel(
        const float* __restrict__ A,
        const float* __restrict__ pin,
        float* __restrict__ pout) {
    __shared__ float p[NN];
    const int b = blockIdx.y;

    // stage pin[b,:] into LDS (coalesced float4, 2 iters of 256 threads)
    const float4* pin4 = (const float4*)(pin + (size_t)b * NN);
    float4* p4 = (float4*)p;
    p4[threadIdx.x]       = pin4[threadIdx.x];
    p4[threadIdx.x + 256] = pin4[threadIdx.x + 256];
    __syncthreads();

    const int wave = threadIdx.x >> 6;
    const int lane = threadIdx.x & 63;
    const int m    = blockIdx.x * 4 + wave;   // this wave's row

    const float4* Ar = (const float4*)(A + (size_t)b * NN * NN + (size_t)m * NN);

    // one burst of 8 independent loads (8 KB per wave in flight)
    float4 x[8];
    #pragma unroll
    for (int j = 0; j < 8; ++j)
        x[j] = Ar[j * 64 + lane];

    float acc = 0.f;
    #pragma unroll
    for (int j = 0; j < 8; ++j) {
        float4 pv = p4[j * 64 + lane];
        acc += x[j].x * pv.x + x[j].y * pv.y + x[j].z * pv.z + x[j].w * pv.w;
    }

    #pragma unroll
    for (int off = 32; off > 0; off >>= 1)
        acc += __shfl_down(acc, off, 64);
    if (lane == 0) pout[(size_t)b * NN + m] = acc;
}

// ---------------------------------------------------------------------------
// Kernel 3: block = 512 threads = 8 waves = the 8 batches of ONE node n.
//   wave w = batch b, lane = channel c.  The 4 strided h[i,c,n] loads are
//   identical across the block's 8 waves -> L1 serves 7 of 8 (8x less
//   uncoalesced fetch than before).  LayerNorm via 64-lane butterfly; tanh;
//   coalesced store.
// ---------------------------------------------------------------------------
__global__ __launch_bounds__(512) void combine_kernel(
        const float* __restrict__ h,      // [4, 64, NN]
        const float* __restrict__ P,      // [4, BB, NN]
        const float* __restrict__ gamma,  // [64]
        const float* __restrict__ beta,   // [64]
        float* __restrict__ out) {        // [BB, NN, 64]
    const int n    = blockIdx.x;          // node
    const int b    = threadIdx.x >> 6;    // batch = wave
    const int lane = threadIdx.x & 63;    // channel
    const int idx  = b * NN + n;          // b*NN + n

    const float p0 = P[0 * BB * NN + idx];
    const float p1 = P[1 * BB * NN + idx];
    const float p2 = P[2 * BB * NN + idx];
    const float p3 = P[3 * BB * NN + idx];

    float y = h[(size_t)(0 * NCH + lane) * NN + n] * p0
            + h[(size_t)(1 * NCH + lane) * NN + n] * p1
            + h[(size_t)(2 * NCH + lane) * NN + n] * p2
            + h[(size_t)(3 * NCH + lane) * NN + n] * p3;

    // mean (all-lanes butterfly)
    float s = y;
    #pragma unroll
    for (int off = 32; off > 0; off >>= 1)
        s += __shfl_xor(s, off, 64);
    const float mean = s * (1.f / NCH);

    float d = y - mean;
    float vs = d * d;
    #pragma unroll
    for (int off = 32; off > 0; off >>= 1)
        vs += __shfl_xor(vs, off, 64);
    const float rstd = rsqrtf(vs * (1.f / NCH) + LN_EPS);

    out[(size_t)idx * NCH + lane] = tanhf(d * rstd * gamma[lane] + beta[lane]);
}

// ---------------------------------------------------------------------------
extern "C" void kernel_launch(void* const* d_in, const int* in_sizes, int n_in,
                              void* d_out, int out_size, void* d_ws, size_t ws_size,
                              hipStream_t stream) {
    const float* A     = (const float*)d_in[0];  // [B, N, N]
    const float* X     = (const float*)d_in[1];  // [B, N, C_IN]
    const float* h     = (const float*)d_in[2];  // [4, 64, N]
    const float* gamma = (const float*)d_in[3];  // [64]
    const float* beta  = (const float*)d_in[4];  // [64]
    float* out = (float*)d_out;                  // [B, N, 64]

    // workspace: P[4][B][N] floats = 256 KB
    float* P = (float*)d_ws;

    // 1) P[0] = Xs = rowsum(X)
    {
        int rows = BB * NN;                 // 16384 rows, 4 rows/block
        xsum_kernel<<<rows / 4, 256, 0, stream>>>(X, P);
    }

    // 2) P[i] = A @ P[i-1], i = 1..3  (sequential dependency)
    dim3 mv_grid(NN / 4, BB);               // one row per wave
    for (int i = 1; i <= NTERMS; ++i) {
        matvec_kernel<<<mv_grid, 256, 0, stream>>>(
            A, P + (size_t)(i - 1) * BB * NN, P + (size_t)i * BB * NN);
    }

    // 3) combine + LayerNorm + tanh: block = all 8 batches of one n
    combine_kernel<<<NN, 512, 0, stream>>>(h, P, gamma, beta, out);
}

// Round 5
// 249.321 us; speedup vs baseline: 1.0614x; 1.0195x over previous
//
#include <hip/hip_runtime.h>
#include <hip/hip_bf16.h>
#include <hip/hip_fp16.h>
#include <math.h>

// Problem constants (match reference)
#define BB 8
#define NN 2048
#define C_IN 64
#define NCH 64
#define NTERMS 3
#define LN_EPS 1e-5f

// ---------------------------------------------------------------------------
// Kernel 1: Xs[b,n] = sum_c X[b,n,c].  one lane per channel, butterfly reduce.
// ---------------------------------------------------------------------------
__global__ void xsum_kernel(const float* __restrict__ X, float* __restrict__ Xs) {
    int row  = (blockIdx.x * blockDim.x + threadIdx.x) >> 6;   // b*NN + n
    int lane = threadIdx.x & 63;
    float v = X[(size_t)row * C_IN + lane];
    #pragma unroll
    for (int off = 32; off > 0; off >>= 1)
        v += __shfl_down(v, off, 64);
    if (lane == 0) Xs[row] = v;
}

// ---------------------------------------------------------------------------
// Kernel 2a: pass 1.  pout[b,m] = dot(A[b,m,:], pin[b,:])  (A fp32)
// AND writes A16[b,m,:] = fp16(A[b,m,:]).
// One row per wave, register-resident p slice, no LDS/barrier.
// ---------------------------------------------------------------------------
__global__ __launch_bounds__(256, 4) void matvec_cvt_kernel(
        const float* __restrict__ A,
        const float* __restrict__ pin,
        float* __restrict__ pout,
        __half* __restrict__ A16) {
    const int b    = blockIdx.y;
    const int wave = threadIdx.x >> 6;
    const int lane = threadIdx.x & 63;
    const int m    = blockIdx.x * 4 + wave;

    const float4* pin4 = (const float4*)(pin + (size_t)b * NN);
    const float4* Ar   = (const float4*)(A + (size_t)b * NN * NN + (size_t)m * NN);

    // burst: 8 independent A loads + 8 independent p loads
    float4 x[8], pr[8];
    #pragma unroll
    for (int j = 0; j < 8; ++j) x[j]  = Ar[j * 64 + lane];
    #pragma unroll
    for (int j = 0; j < 8; ++j) pr[j] = pin4[j * 64 + lane];

    float acc = 0.f;
    #pragma unroll
    for (int j = 0; j < 8; ++j)
        acc += x[j].x * pr[j].x + x[j].y * pr[j].y + x[j].z * pr[j].z + x[j].w * pr[j].w;

    // write fp16 copy of the row: 4 floats -> 8 bytes per j, coalesced
    float2* A16r = (float2*)(A16 + (size_t)b * NN * NN + (size_t)m * NN);
    #pragma unroll
    for (int j = 0; j < 8; ++j) {
        union { float2 f2; __half2 h2[2]; } u;
        u.h2[0] = __floats2half2_rn(x[j].x, x[j].y);
        u.h2[1] = __floats2half2_rn(x[j].z, x[j].w);
        A16r[j * 64 + lane] = u.f2;
    }

    #pragma unroll
    for (int off = 32; off > 0; off >>= 1)
        acc += __shfl_down(acc, off, 64);
    if (lane == 0) pout[(size_t)b * NN + m] = acc;
}

// ---------------------------------------------------------------------------
// Kernel 2b: passes 2..T.  pout[b,m] = dot(A16[b,m,:], pin[b,:])  (A fp16)
// Row = 4 KB: 4 float4-sized loads of 8 halves.  p slice (8 floats per lane
// per chunk) loaded as two float4 from global (L1/L2-hot, 8 KB per batch).
// ---------------------------------------------------------------------------
__global__ __launch_bounds__(256, 4) void matvec16_kernel(
        const __half* __restrict__ A16,
        const float* __restrict__ pin,
        float* __restrict__ pout) {
    const int b    = blockIdx.y;
    const int wave = threadIdx.x >> 6;
    const int lane = threadIdx.x & 63;
    const int m    = blockIdx.x * 4 + wave;

    const float4* pin4 = (const float4*)(pin + (size_t)b * NN);
    const float4* Ar   = (const float4*)(A16 + (size_t)b * NN * NN + (size_t)m * NN);

    float4 xr[4], pa[4], pb[4];
    #pragma unroll
    for (int j = 0; j < 4; ++j) xr[j] = Ar[j * 64 + lane];        // 8 halves each
    #pragma unroll
    for (int j = 0; j < 4; ++j) {
        pa[j] = pin4[2 * (j * 64 + lane)];                         // floats 8k..8k+3
        pb[j] = pin4[2 * (j * 64 + lane) + 1];                     // floats 8k+4..8k+7
    }

    float acc = 0.f;
    #pragma unroll
    for (int j = 0; j < 4; ++j) {
        const __half2* hx = (const __half2*)&xr[j];
        float2 f0 = __half22float2(hx[0]);
        float2 f1 = __half22float2(hx[1]);
        float2 f2 = __half22float2(hx[2]);
        float2 f3 = __half22float2(hx[3]);
        acc += f0.x * pa[j].x + f0.y * pa[j].y + f1.x * pa[j].z + f1.y * pa[j].w
             + f2.x * pb[j].x + f2.y * pb[j].y + f3.x * pb[j].z + f3.y * pb[j].w;
    }

    #pragma unroll
    for (int off = 32; off > 0; off >>= 1)
        acc += __shfl_down(acc, off, 64);
    if (lane == 0) pout[(size_t)b * NN + m] = acc;
}

// ---------------------------------------------------------------------------
// Kernel 3: block = 512 threads = 8 waves = the 8 batches of ONE node n.
// wave = batch, lane = channel; LayerNorm via butterfly; tanh; coalesced store.
// ---------------------------------------------------------------------------
__global__ __launch_bounds__(512) void combine_kernel(
        const float* __restrict__ h,      // [4, 64, NN]
        const float* __restrict__ P,      // [4, BB, NN]
        const float* __restrict__ gamma,  // [64]
        const float* __restrict__ beta,   // [64]
        float* __restrict__ out) {        // [BB, NN, 64]
    const int n    = blockIdx.x;
    const int b    = threadIdx.x >> 6;
    const int lane = threadIdx.x & 63;
    const int idx  = b * NN + n;

    const float p0 = P[0 * BB * NN + idx];
    const float p1 = P[1 * BB * NN + idx];
    const float p2 = P[2 * BB * NN + idx];
    const float p3 = P[3 * BB * NN + idx];

    float y = h[(size_t)(0 * NCH + lane) * NN + n] * p0
            + h[(size_t)(1 * NCH + lane) * NN + n] * p1
            + h[(size_t)(2 * NCH + lane) * NN + n] * p2
            + h[(size_t)(3 * NCH + lane) * NN + n] * p3;

    float s = y;
    #pragma unroll
    for (int off = 32; off > 0; off >>= 1)
        s += __shfl_xor(s, off, 64);
    const float mean = s * (1.f / NCH);

    float d = y - mean;
    float vs = d * d;
    #pragma unroll
    for (int off = 32; off > 0; off >>= 1)
        vs += __shfl_xor(vs, off, 64);
    const float rstd = rsqrtf(vs * (1.f / NCH) + LN_EPS);

    out[(size_t)idx * NCH + lane] = tanhf(d * rstd * gamma[lane] + beta[lane]);
}

// ---------------------------------------------------------------------------
extern "C" void kernel_launch(void* const* d_in, const int* in_sizes, int n_in,
                              void* d_out, int out_size, void* d_ws, size_t ws_size,
                              hipStream_t stream) {
    const float* A     = (const float*)d_in[0];  // [B, N, N]
    const float* X     = (const float*)d_in[1];  // [B, N, C_IN]
    const float* h     = (const float*)d_in[2];  // [4, 64, N]
    const float* gamma = (const float*)d_in[3];  // [64]
    const float* beta  = (const float*)d_in[4];  // [64]
    float* out = (float*)d_out;                  // [B, N, 64]

    // workspace layout: P[4][B][N] floats (256 KB), then A16 at +1 MB (67 MB)
    float*  P   = (float*)d_ws;
    __half* A16 = (__half*)((char*)d_ws + (1u << 20));

    // 1) P[0] = Xs = rowsum(X)
    xsum_kernel<<<(BB * NN) / 4, 256, 0, stream>>>(X, P);

    // 2) P[1] = A @ P[0]  (fp32 A, emits fp16 copy of A)
    dim3 mv_grid(NN / 4, BB);
    matvec_cvt_kernel<<<mv_grid, 256, 0, stream>>>(A, P, P + BB * NN, A16);

    //    P[i] = A16 @ P[i-1], i = 2..3  (half the bytes)
    for (int i = 2; i <= NTERMS; ++i) {
        matvec16_kernel<<<mv_grid, 256, 0, stream>>>(
            A16, P + (size_t)(i - 1) * BB * NN, P + (size_t)i * BB * NN);
    }

    // 3) combine + LayerNorm + tanh
    combine_kernel<<<NN, 512, 0, stream>>>(h, P, gamma, beta, out);
}